// Round 1
// 379.130 us; speedup vs baseline: 1.1164x; 1.1164x over previous
//
// MultiHeadAttention pipeline for MI355X (gfx950)
// R8: GEMMs rewritten to the T3+T4+T5 stack (counted-vmcnt phased pipeline):
//   - BM=128 x BN=256, BK=64, 8 waves (512 thr), per-wave 64x64 output.
//   - Grid quantization exact: qkv 24x32=768=3 rounds, proj 8x32=256=1 round.
//   - Triple-buffered LDS (3 x 48 KiB = 144 KiB), prefetch 2 K-tiles ahead,
//     s_waitcnt vmcnt(9) steady state -- never drained to 0 in the loop.
//   - Raw s_barrier (no compiler vmcnt(0) drain), setprio(1) around MFMA.
//   - XOR swizzle (colgroup ^ row&7) on pre-swizzled global src + ds_read.
// attn kernel unchanged from R7.
#include <hip/hip_runtime.h>
#include <stdint.h>

typedef __attribute__((ext_vector_type(8))) short vshort8;
typedef __attribute__((ext_vector_type(4))) short vshort4;
typedef __attribute__((ext_vector_type(4))) float vfloat4;

__device__ __forceinline__ short f2bf(float f) {
  union { float f; uint32_t u; } v; v.f = f;
  uint32_t r = (v.u + 0x7FFFu + ((v.u >> 16) & 1u)) >> 16;
  return (short)r;
}
__device__ __forceinline__ void gl_lds16(const void* g, void* l) {
  __builtin_amdgcn_global_load_lds(
      (const __attribute__((address_space(1))) void*)g,
      (__attribute__((address_space(3))) void*)l, 16, 0, 0);
}

// fp32 -> bf16 (RNE), 8 elements/thread
__global__ void cvt_kernel(const float* __restrict__ src, short* __restrict__ dst,
                           int n) {
  int i = (blockIdx.x * blockDim.x + threadIdx.x) * 8;
  if (i >= n) return;
  vfloat4 a = *(const vfloat4*)(src + i);
  vfloat4 b = *(const vfloat4*)(src + i + 4);
  vshort8 o;
#pragma unroll
  for (int j = 0; j < 4; ++j) { o[j] = f2bf(a[j]); o[j + 4] = f2bf(b[j]); }
  *(vshort8*)(dst + i) = o;
}

// three fp32 sources -> one concatenated bf16 dst [3][n]
__global__ void cvt3_kernel(const float* __restrict__ s0, const float* __restrict__ s1,
                            const float* __restrict__ s2, short* __restrict__ dst, int n) {
  const float* s = (blockIdx.y == 0) ? s0 : ((blockIdx.y == 1) ? s1 : s2);
  int i = (blockIdx.x * blockDim.x + threadIdx.x) * 8;
  if (i >= n) return;
  vfloat4 a = *(const vfloat4*)(s + i);
  vfloat4 b = *(const vfloat4*)(s + i + 4);
  vshort8 o;
#pragma unroll
  for (int j = 0; j < 4; ++j) { o[j] = f2bf(a[j]); o[j + 4] = f2bf(b[j]); }
  *(vshort8*)(dst + (size_t)blockIdx.y * n + i) = o;
}

// ---------------------------------------------------------------------------
// Pipelined GEMM core, shared by gemm_qkv / gemm_proj.
// C[m][n] = sum_k A[m][k] * B[n][k]   (both row-major [rows][K], bf16)
// Block tile 128(M) x 256(N), BK=64. 8 waves: wr=w>>2 (2 x 64 rows),
// wc=w&3 (4 x 64 cols). Per-wave acc[4][4] of 16x16 fragments.
// LDS per buffer: A 128x64 (8192 shorts) | B 256x64 (16384 shorts).
// Swizzle: 16B column-group g stored at slot g ^ (row & 7).
// ---------------------------------------------------------------------------
#define GEMM_MAIN_LOOP()                                                        \
  const int tid  = threadIdx.x;                                                 \
  const int lane = tid & 63;                                                    \
  const int w    = tid >> 6;                                                    \
  const int wr   = w >> 2;                                                      \
  const int wc   = w & 3;                                                       \
  const int lrow = lane & 15;                                                   \
  const int quad = lane >> 4;                                                   \
  const int swz  = lrow & 7;                                                    \
  const int m0   = blockIdx.y * 128;                                            \
  const int n0   = blockIdx.x * 256;                                            \
  const int rr   = tid >> 3;                                                    \
  const int cg8  = ((tid & 7) ^ ((tid >> 3) & 7)) * 8;                          \
  const short* Ag = Aptr + (size_t)(m0 + rr) * K + cg8;                         \
  const short* Bg = Bptr + (size_t)(n0 + rr) * K + cg8;                         \
  auto stageA = [&](int bb, int kt, int i) {                                    \
    gl_lds16(Ag + (size_t)i * 64 * K + (size_t)kt * 64,                         \
             (void*)&lds[bb][i * 4096 + tid * 8]);                              \
  };                                                                            \
  auto stageB = [&](int bb, int kt, int i) {                                    \
    gl_lds16(Bg + (size_t)i * 64 * K + (size_t)kt * 64,                         \
             (void*)&lds[bb][8192 + i * 4096 + tid * 8]);                       \
  };                                                                            \
  const int aoff = (wr * 64 + lrow) * 64;                                       \
  const int boff = (wc * 64 + lrow) * 64;                                       \
  const int g8a0 = (quad ^ swz) * 8;                                            \
  const int g8a1 = ((4 + quad) ^ swz) * 8;                                      \
  vfloat4 acc[4][4] = {};                                                       \
  const int NT = K >> 6;                                                        \
  /* prologue: tiles 0 and 1 fully staged into bufs 0,1 */                      \
  stageA(0, 0, 0); stageA(0, 0, 1);                                             \
  stageB(0, 0, 0); stageB(0, 0, 1); stageB(0, 0, 2); stageB(0, 0, 3);           \
  stageA(1, 1, 0); stageA(1, 1, 1);                                             \
  stageB(1, 1, 0); stageB(1, 1, 1); stageB(1, 1, 2); stageB(1, 1, 3);           \
  int cbuf = 0;                                                                 \
  for (int t = 0; t < NT; ++t) {                                                \
    const short* As = lds[cbuf];                                                \
    const short* Bs = lds[cbuf] + 8192;                                         \
    const int sb = (cbuf == 0) ? 2 : cbuf - 1; /* buf for tile t+2 */           \
    /* ---- tile-ready sync (counted vmcnt, not 0) ---- */                      \
    if (t + 2 < NT) {                                                           \
      stageA(sb, t + 2, 0); stageA(sb, t + 2, 1); stageB(sb, t + 2, 0);         \
      asm volatile("s_waitcnt vmcnt(9)" ::: "memory");                          \
    } else if (t + 1 < NT) {                                                    \
      asm volatile("s_waitcnt vmcnt(6)" ::: "memory");                          \
    } else {                                                                    \
      asm volatile("s_waitcnt vmcnt(0)" ::: "memory");                          \
    }                                                                           \
    __builtin_amdgcn_s_barrier();                                               \
    __builtin_amdgcn_sched_barrier(0);                                          \
    /* ---- phase 0: m-half 0 x all n ---- */                                   \
    vshort8 a0[2][2], b[4][2];                                                  \
    _Pragma("unroll") for (int mi = 0; mi < 2; ++mi) {                          \
      a0[mi][0] = *(const vshort8*)(As + aoff + mi * 1024 + g8a0);              \
      a0[mi][1] = *(const vshort8*)(As + aoff + mi * 1024 + g8a1);              \
    }                                                                           \
    _Pragma("unroll") for (int ni = 0; ni < 4; ++ni) {                          \
      b[ni][0] = *(const vshort8*)(Bs + boff + ni * 1024 + g8a0);               \
      b[ni][1] = *(const vshort8*)(Bs + boff + ni * 1024 + g8a1);               \
    }                                                                           \
    asm volatile("s_waitcnt lgkmcnt(0)" ::: "memory");                          \
    __builtin_amdgcn_sched_barrier(0);                                          \
    __builtin_amdgcn_s_setprio(1);                                              \
    _Pragma("unroll") for (int mi = 0; mi < 2; ++mi)                            \
      _Pragma("unroll") for (int ni = 0; ni < 4; ++ni)                          \
        _Pragma("unroll") for (int ks = 0; ks < 2; ++ks)                        \
          acc[mi][ni] = __builtin_amdgcn_mfma_f32_16x16x32_bf16(                \
              a0[mi][ks], b[ni][ks], acc[mi][ni], 0, 0, 0);                     \
    __builtin_amdgcn_s_setprio(0);                                              \
    __builtin_amdgcn_s_barrier();                                               \
    /* ---- phase 1: m-half 1 x all n ---- */                                   \
    vshort8 a1[2][2];                                                           \
    _Pragma("unroll") for (int mi = 0; mi < 2; ++mi) {                          \
      a1[mi][0] = *(const vshort8*)(As + aoff + (2 + mi) * 1024 + g8a0);        \
      a1[mi][1] = *(const vshort8*)(As + aoff + (2 + mi) * 1024 + g8a1);        \
    }                                                                           \
    if (t + 2 < NT) {                                                           \
      stageB(sb, t + 2, 1); stageB(sb, t + 2, 2); stageB(sb, t + 2, 3);         \
    }                                                                           \
    asm volatile("s_waitcnt lgkmcnt(0)" ::: "memory");                          \
    __builtin_amdgcn_sched_barrier(0);                                          \
    __builtin_amdgcn_s_setprio(1);                                              \
    _Pragma("unroll") for (int mi = 0; mi < 2; ++mi)                            \
      _Pragma("unroll") for (int ni = 0; ni < 4; ++ni)                          \
        _Pragma("unroll") for (int ks = 0; ks < 2; ++ks)                        \
          acc[2 + mi][ni] = __builtin_amdgcn_mfma_f32_16x16x32_bf16(            \
              a1[mi][ks], b[ni][ks], acc[2 + mi][ni], 0, 0, 0);                 \
    __builtin_amdgcn_s_setprio(0);                                              \
    __builtin_amdgcn_s_barrier();                                               \
    __builtin_amdgcn_sched_barrier(0);                                          \
    cbuf = (cbuf == 2) ? 0 : cbuf + 1;                                          \
  }

// Fused QKV: C[m][n'] = sum_k A[m][k]*Wcat[n'][k], n' in [0,6144).
// Region 0 (n'<2048): Qw[m][n]*scale; region 1: Kw[m][n]; region 2: Vtw[n][m].
__global__ __launch_bounds__(512, 2) void gemm_qkv(
    const short* __restrict__ Aptr, const short* __restrict__ Bptr,
    short* __restrict__ Qw, short* __restrict__ Kw, short* __restrict__ Vtw,
    int M, int K, float scale) {
  __shared__ __attribute__((aligned(16))) short lds[3][24576];
  GEMM_MAIN_LOOP()

  const int region = n0 >> 11;  // uniform per block (2048 % 256 == 0)
#pragma unroll
  for (int mi = 0; mi < 4; ++mi) {
    int mbase = m0 + wr * 64 + mi * 16 + quad * 4;
#pragma unroll
    for (int ni = 0; ni < 4; ++ni) {
      int ng = n0 + wc * 64 + ni * 16 + lrow;
      int nn = ng & 2047;
      if (region == 2) {
        vshort4 sv;
#pragma unroll
        for (int r = 0; r < 4; ++r) sv[r] = f2bf(acc[mi][ni][r]);
        *(vshort4*)(Vtw + (size_t)nn * 4096 + mbase) = sv;
      } else if (region == 0) {
#pragma unroll
        for (int r = 0; r < 4; ++r)
          Qw[(size_t)(mbase + r) * 2048 + nn] = f2bf(acc[mi][ni][r] * scale);
      } else {
#pragma unroll
        for (int r = 0; r < 4; ++r)
          Kw[(size_t)(mbase + r) * 2048 + nn] = f2bf(acc[mi][ni][r]);
      }
    }
  }
}

// Output projection: fp32 store + fp32 bias
__global__ __launch_bounds__(512, 2) void gemm_proj(
    const short* __restrict__ Aptr, const short* __restrict__ Bptr,
    float* __restrict__ C, const float* __restrict__ bias,
    int M, int K, int ldC) {
  __shared__ __attribute__((aligned(16))) short lds[3][24576];
  GEMM_MAIN_LOOP()

#pragma unroll
  for (int mi = 0; mi < 4; ++mi) {
    int mbase = m0 + wr * 64 + mi * 16 + quad * 4;
#pragma unroll
    for (int ni = 0; ni < 4; ++ni) {
      int n = n0 + wc * 64 + ni * 16 + lrow;
      float badd = bias[n];
#pragma unroll
      for (int r = 0; r < 4; ++r)
        C[(size_t)(mbase + r) * ldC + n] = acc[mi][ni][r] + badd;
    }
  }
}

// Flash attention, fixed-max softmax (M=12), row-sum via ones-row MFMA.
// Block = Q-tile pair {p, 31-p} for one (b,h); 33 K-tile iters each.
__global__ __launch_bounds__(256) void attn_kernel(
    const short* __restrict__ Q, const short* __restrict__ Kg,
    const short* __restrict__ Vt, const int* __restrict__ pm,
    short* __restrict__ ctx) {
  const int T = 2048, Cd = 2048, D = 128, MT = 4096;
  __shared__ __attribute__((aligned(16))) short Ks[64][136];
  __shared__ __attribute__((aligned(16))) short Vs[144][72];  // 128..143: ones/zero rows
  __shared__ __attribute__((aligned(16))) short Ps[4][16][72];

  const int tid  = threadIdx.x;
  const int lane = tid & 63;
  const int w    = tid >> 6;
  const int lrow = lane & 15;
  const int quad = lane >> 4;
  const int p = blockIdx.x, h = blockIdx.y, b = blockIdx.z;

  // init sum-helper rows: row 128 = 1.0 (bf16 0x3F80), rows 129..143 = 0
  for (int i = tid; i < 16 * 72; i += 256) {
    int rr = i / 72, cc = i % 72;
    Vs[128 + rr][cc] = (rr == 0) ? (short)0x3F80 : (short)0;
  }

#pragma unroll 1
  for (int tt = 0; tt < 2; ++tt) {
    const int qt = tt ? (31 - p) : p;
    const int q0 = qt * 64;
    const int qrow = q0 + w * 16 + quad * 4;

    vshort8 qf[4];
#pragma unroll
    for (int ks = 0; ks < 4; ++ks)
      qf[ks] = *(const vshort8*)(Q + (size_t)(b * T + q0 + w * 16 + lrow) * Cd +
                                 h * D + ks * 32 + quad * 8);
    bool keep[4];
#pragma unroll
    for (int r = 0; r < 4; ++r) keep[r] = pm[b * T + qrow + r] != 0;

    vfloat4 oacc[8] = {};
    vfloat4 osum = {};  // row-sum accumulator (col 0 = d128 ones-row)

    __syncthreads();
#pragma unroll
    for (int i = 0; i < 4; ++i) {
      int c = tid + i * 256;
      int kr = c >> 4, kc = c & 15;
      *(vfloat4*)(&Ks[kr][kc * 8]) =
          *(const vfloat4*)(Kg + (size_t)(b * T + kr) * Cd + h * D + kc * 8);
      int vr = c >> 3, vc = c & 7;
      *(vfloat4*)(&Vs[vr][vc * 8]) =
          *(const vfloat4*)(Vt + (size_t)(h * D + vr) * MT + b * T + vc * 8);
    }
    __syncthreads();

#pragma unroll 1
    for (int j = 0; j <= qt; ++j) {
      const int jn = (j < qt) ? (j + 1) : qt;
      vfloat4 pk[4], pv[4];
#pragma unroll
      for (int i = 0; i < 4; ++i) {
        int c = tid + i * 256;
        int kr = c >> 4, kc = c & 15;
        pk[i] = *(const vfloat4*)(Kg + (size_t)(b * T + jn * 64 + kr) * Cd + h * D + kc * 8);
        int vr = c >> 3, vc = c & 7;
        pv[i] = *(const vfloat4*)(Vt + (size_t)(h * D + vr) * MT + b * T + jn * 64 + vc * 8);
      }

      // QK^T
      vfloat4 sacc[4] = {};
#pragma unroll
      for (int nt = 0; nt < 4; ++nt)
#pragma unroll
        for (int ks = 0; ks < 4; ++ks) {
          vshort8 kf = *(const vshort8*)(&Ks[nt * 16 + lrow][ks * 32 + quad * 8]);
          sacc[nt] = __builtin_amdgcn_mfma_f32_16x16x32_bf16(qf[ks], kf, sacc[nt], 0, 0, 0);
        }

      // fixed-max softmax: p = exp(s - 12); padded rows -> s=0 (uniform);
      // causal future -> p = 0 exactly. Write P in A-layout via LDS.
#pragma unroll
      for (int nt = 0; nt < 4; ++nt) {
        int s_idx = j * 64 + nt * 16 + lrow;
#pragma unroll
        for (int r = 0; r < 4; ++r) {
          float sv = keep[r] ? sacc[nt][r] : 0.0f;
          float pe = __expf(sv - 12.0f);
          pe = (s_idx <= qrow + r) ? pe : 0.0f;
          Ps[w][quad * 4 + r][nt * 16 + lrow] = f2bf(pe);
        }
      }

      vshort8 pf[2];
#pragma unroll
      for (int kp = 0; kp < 2; ++kp)
        pf[kp] = *(const vshort8*)(&Ps[w][lrow][kp * 32 + quad * 8]);
#pragma unroll
      for (int dt = 0; dt < 8; ++dt)
#pragma unroll
        for (int kp = 0; kp < 2; ++kp) {
          vshort8 vf = *(const vshort8*)(&Vs[dt * 16 + lrow][kp * 32 + quad * 8]);
          oacc[dt] = __builtin_amdgcn_mfma_f32_16x16x32_bf16(pf[kp], vf, oacc[dt], 0, 0, 0);
        }
      // row sums via ones-row tile (d = 128..143)
#pragma unroll
      for (int kp = 0; kp < 2; ++kp) {
        vshort8 vf = *(const vshort8*)(&Vs[128 + lrow][kp * 32 + quad * 8]);
        osum = __builtin_amdgcn_mfma_f32_16x16x32_bf16(pf[kp], vf, osum, 0, 0, 0);
      }

      __syncthreads();
#pragma unroll
      for (int i = 0; i < 4; ++i) {
        int c = tid + i * 256;
        int kr = c >> 4, kc = c & 15;
        *(vfloat4*)(&Ks[kr][kc * 8]) = pk[i];
        int vr = c >> 3, vc = c & 7;
        *(vfloat4*)(&Vs[vr][vc * 8]) = pv[i];
      }
      __syncthreads();
    }

    // l[r] lives at col 0 of osum = lane quad*16, reg r
    float l[4];
#pragma unroll
    for (int r = 0; r < 4; ++r)
      l[r] = fmaxf(__shfl(osum[r], (lane & 48), 64), 1e-30f);

#pragma unroll
    for (int dt = 0; dt < 8; ++dt) {
      int d = dt * 16 + lrow;
#pragma unroll
      for (int r = 0; r < 4; ++r) {
        float o = oacc[dt][r] / l[r];
        ctx[(size_t)(b * T + qrow + r) * Cd + h * D + d] = f2bf(o);
      }
    }
  }
}

extern "C" void kernel_launch(void* const* d_in, const int* in_sizes, int n_in,
                              void* d_out, int out_size, void* d_ws, size_t ws_size,
                              hipStream_t stream) {
  (void)in_sizes; (void)n_in; (void)out_size; (void)ws_size;
  const float* x  = (const float*)d_in[0];
  const int*   pm = (const int*)d_in[1];
  const float* Wq = (const float*)d_in[2];
  const float* Wk = (const float*)d_in[3];
  const float* Wv = (const float*)d_in[4];
  const float* Wp = (const float*)d_in[5];
  const float* bp = (const float*)d_in[6];
  float* out = (float*)d_out;

  const int Bb = 2, T = 2048, Cd = 2048, M = Bb * T;  // M = 4096
  const size_t SZ = (size_t)M * Cd;   // 8.4M
  const size_t WZ = (size_t)Cd * Cd;  // 4.2M
  short* xb   = (short*)d_ws;         // [M][C]
  short* Qw   = xb + SZ;              // [M][C] (pre-scaled)
  short* Kw   = Qw + SZ;              // [M][C]
  short* Vtw  = Kw + SZ;              // [C][M]
  short* Cx   = Vtw + SZ;             // [M][C]
  short* wcat = Cx + SZ;              // [3C][C] QKV weights; reused for Wp

  const int CB = 256;
  dim3 gx(((int)SZ / 8 + CB - 1) / CB);
  dim3 gw(((int)WZ / 8 + CB - 1) / CB);
  const float scale = 0.08838834764831845f;  // 1/sqrt(128)

  cvt_kernel<<<gx, CB, 0, stream>>>(x, xb, (int)SZ);
  cvt3_kernel<<<dim3(gw.x, 3), CB, 0, stream>>>(Wq, Wk, Wv, wcat, (int)WZ);

  gemm_qkv<<<dim3(6144 / 256, M / 128), 512, 0, stream>>>(
      xb, wcat, Qw, Kw, Vtw, M, Cd, scale);

  attn_kernel<<<dim3(16, 16, Bb), 256, 0, stream>>>(Qw, Kw, Vtw, pm, Cx);

  cvt_kernel<<<gw, CB, 0, stream>>>(Wp, wcat, (int)WZ);
  gemm_proj<<<dim3(Cd / 256, M / 128), 512, 0, stream>>>(Cx, wcat, out, bp, M, Cd, Cd);
}

// Round 2
// 373.080 us; speedup vs baseline: 1.1345x; 1.0162x over previous
//
// MultiHeadAttention pipeline for MI355X (gfx950)
// R9: GEMM K-loop restructured: ONE barrier per K-tile, no manual lgkmcnt
//   drains. Per tile: vmcnt(6) -> s_barrier -> stage t+2 (6 gl_lds) ->
//   issue all 16 ds_read_b128 -> 32 MFMA (compiler emits counted lgkmcnt).
//   Removes the per-phase read-drain/MFMA serialization that held R8 at
//   MfmaUtil 34.6% (3144 cyc/tile vs 1210 MFMA floor).
//   Triple-buffer unchanged; stage for t+2 moved AFTER the barrier (it
//   overwrites the buffer read at t-1, which all waves finished pre-barrier).
// attn kernel unchanged from R7.
#include <hip/hip_runtime.h>
#include <stdint.h>

typedef __attribute__((ext_vector_type(8))) short vshort8;
typedef __attribute__((ext_vector_type(4))) short vshort4;
typedef __attribute__((ext_vector_type(4))) float vfloat4;

__device__ __forceinline__ short f2bf(float f) {
  union { float f; uint32_t u; } v; v.f = f;
  uint32_t r = (v.u + 0x7FFFu + ((v.u >> 16) & 1u)) >> 16;
  return (short)r;
}
__device__ __forceinline__ void gl_lds16(const void* g, void* l) {
  __builtin_amdgcn_global_load_lds(
      (const __attribute__((address_space(1))) void*)g,
      (__attribute__((address_space(3))) void*)l, 16, 0, 0);
}

// fp32 -> bf16 (RNE), 8 elements/thread
__global__ void cvt_kernel(const float* __restrict__ src, short* __restrict__ dst,
                           int n) {
  int i = (blockIdx.x * blockDim.x + threadIdx.x) * 8;
  if (i >= n) return;
  vfloat4 a = *(const vfloat4*)(src + i);
  vfloat4 b = *(const vfloat4*)(src + i + 4);
  vshort8 o;
#pragma unroll
  for (int j = 0; j < 4; ++j) { o[j] = f2bf(a[j]); o[j + 4] = f2bf(b[j]); }
  *(vshort8*)(dst + i) = o;
}

// three fp32 sources -> one concatenated bf16 dst [3][n]
__global__ void cvt3_kernel(const float* __restrict__ s0, const float* __restrict__ s1,
                            const float* __restrict__ s2, short* __restrict__ dst, int n) {
  const float* s = (blockIdx.y == 0) ? s0 : ((blockIdx.y == 1) ? s1 : s2);
  int i = (blockIdx.x * blockDim.x + threadIdx.x) * 8;
  if (i >= n) return;
  vfloat4 a = *(const vfloat4*)(s + i);
  vfloat4 b = *(const vfloat4*)(s + i + 4);
  vshort8 o;
#pragma unroll
  for (int j = 0; j < 4; ++j) { o[j] = f2bf(a[j]); o[j + 4] = f2bf(b[j]); }
  *(vshort8*)(dst + (size_t)blockIdx.y * n + i) = o;
}

// ---------------------------------------------------------------------------
// Pipelined GEMM core, shared by gemm_qkv / gemm_proj.
// C[m][n] = sum_k A[m][k] * B[n][k]   (both row-major [rows][K], bf16)
// Block tile 128(M) x 256(N), BK=64. 8 waves: wr=w>>2 (2 x 64 rows),
// wc=w&3 (4 x 64 cols). Per-wave acc[4][4] of 16x16 fragments.
// LDS per buffer: A 128x64 (8192 shorts) | B 256x64 (16384 shorts).
// Swizzle: 16B column-group g stored at slot g ^ (row & 7).
// Schedule: 1 barrier/tile; counted vmcnt(6); compiler-counted lgkmcnt.
// ---------------------------------------------------------------------------
#define GEMM_MAIN_LOOP()                                                        \
  const int tid  = threadIdx.x;                                                 \
  const int lane = tid & 63;                                                    \
  const int w    = tid >> 6;                                                    \
  const int wr   = w >> 2;                                                      \
  const int wc   = w & 3;                                                       \
  const int lrow = lane & 15;                                                   \
  const int quad = lane >> 4;                                                   \
  const int swz  = lrow & 7;                                                    \
  const int m0   = blockIdx.y * 128;                                            \
  const int n0   = blockIdx.x * 256;                                            \
  const int rr   = tid >> 3;                                                    \
  const int cg8  = ((tid & 7) ^ ((tid >> 3) & 7)) * 8;                          \
  const short* Ag = Aptr + (size_t)(m0 + rr) * K + cg8;                         \
  const short* Bg = Bptr + (size_t)(n0 + rr) * K + cg8;                         \
  auto stageA = [&](int bb, int kt, int i) {                                    \
    gl_lds16(Ag + (size_t)i * 64 * K + (size_t)kt * 64,                         \
             (void*)&lds[bb][i * 4096 + tid * 8]);                              \
  };                                                                            \
  auto stageB = [&](int bb, int kt, int i) {                                    \
    gl_lds16(Bg + (size_t)i * 64 * K + (size_t)kt * 64,                         \
             (void*)&lds[bb][8192 + i * 4096 + tid * 8]);                       \
  };                                                                            \
  const int aoff = (wr * 64 + lrow) * 64;                                       \
  const int boff = (wc * 64 + lrow) * 64;                                       \
  const int g8a0 = (quad ^ swz) * 8;                                            \
  const int g8a1 = ((4 + quad) ^ swz) * 8;                                      \
  vfloat4 acc[4][4] = {};                                                       \
  const int NT = K >> 6;                                                        \
  /* prologue: tiles 0 and 1 fully staged into bufs 0,1 */                      \
  stageA(0, 0, 0); stageA(0, 0, 1);                                             \
  stageB(0, 0, 0); stageB(0, 0, 1); stageB(0, 0, 2); stageB(0, 0, 3);           \
  stageA(1, 1, 0); stageA(1, 1, 1);                                             \
  stageB(1, 1, 0); stageB(1, 1, 1); stageB(1, 1, 2); stageB(1, 1, 3);           \
  int cbuf = 0;                                                                 \
  for (int t = 0; t < NT; ++t) {                                                \
    const short* As = lds[cbuf];                                                \
    const short* Bs = lds[cbuf] + 8192;                                         \
    const int sb = (cbuf == 0) ? 2 : cbuf - 1; /* buf for tile t+2 */           \
    /* tile-ready: drain this tile's 6 stages, keep t+1's 6 in flight */        \
    if (t + 1 < NT) {                                                           \
      asm volatile("s_waitcnt vmcnt(6)" ::: "memory");                          \
    } else {                                                                    \
      asm volatile("s_waitcnt vmcnt(0)" ::: "memory");                          \
    }                                                                           \
    __builtin_amdgcn_s_barrier();                                               \
    __builtin_amdgcn_sched_barrier(0);                                          \
    /* prefetch tile t+2 (buffer was read at t-1; all waves past it now) */     \
    if (t + 2 < NT) {                                                           \
      stageA(sb, t + 2, 0); stageA(sb, t + 2, 1);                               \
      stageB(sb, t + 2, 0); stageB(sb, t + 2, 1);                               \
      stageB(sb, t + 2, 2); stageB(sb, t + 2, 3);                               \
    }                                                                           \
    /* issue all fragment reads; compiler interleaves counted lgkmcnt waits */  \
    vshort8 a[4][2], b[4][2];                                                   \
    _Pragma("unroll") for (int i = 0; i < 4; ++i) {                             \
      a[i][0] = *(const vshort8*)(As + aoff + i * 1024 + g8a0);                 \
      a[i][1] = *(const vshort8*)(As + aoff + i * 1024 + g8a1);                 \
      b[i][0] = *(const vshort8*)(Bs + boff + i * 1024 + g8a0);                 \
      b[i][1] = *(const vshort8*)(Bs + boff + i * 1024 + g8a1);                 \
    }                                                                           \
    __builtin_amdgcn_s_setprio(1);                                              \
    _Pragma("unroll") for (int mi = 0; mi < 4; ++mi)                            \
      _Pragma("unroll") for (int ni = 0; ni < 4; ++ni)                          \
        _Pragma("unroll") for (int ks = 0; ks < 2; ++ks)                        \
          acc[mi][ni] = __builtin_amdgcn_mfma_f32_16x16x32_bf16(                \
              a[mi][ks], b[ni][ks], acc[mi][ni], 0, 0, 0);                      \
    __builtin_amdgcn_s_setprio(0);                                              \
    __builtin_amdgcn_sched_barrier(0);                                          \
    cbuf = (cbuf == 2) ? 0 : cbuf + 1;                                          \
  }

// Fused QKV: C[m][n'] = sum_k A[m][k]*Wcat[n'][k], n' in [0,6144).
// Region 0 (n'<2048): Qw[m][n]*scale; region 1: Kw[m][n]; region 2: Vtw[n][m].
__global__ __launch_bounds__(512, 2) void gemm_qkv(
    const short* __restrict__ Aptr, const short* __restrict__ Bptr,
    short* __restrict__ Qw, short* __restrict__ Kw, short* __restrict__ Vtw,
    int M, int K, float scale) {
  __shared__ __attribute__((aligned(16))) short lds[3][24576];
  GEMM_MAIN_LOOP()

  const int region = n0 >> 11;  // uniform per block (2048 % 256 == 0)
#pragma unroll
  for (int mi = 0; mi < 4; ++mi) {
    int mbase = m0 + wr * 64 + mi * 16 + quad * 4;
#pragma unroll
    for (int ni = 0; ni < 4; ++ni) {
      int ng = n0 + wc * 64 + ni * 16 + lrow;
      int nn = ng & 2047;
      if (region == 2) {
        vshort4 sv;
#pragma unroll
        for (int r = 0; r < 4; ++r) sv[r] = f2bf(acc[mi][ni][r]);
        *(vshort4*)(Vtw + (size_t)nn * 4096 + mbase) = sv;
      } else if (region == 0) {
#pragma unroll
        for (int r = 0; r < 4; ++r)
          Qw[(size_t)(mbase + r) * 2048 + nn] = f2bf(acc[mi][ni][r] * scale);
      } else {
#pragma unroll
        for (int r = 0; r < 4; ++r)
          Kw[(size_t)(mbase + r) * 2048 + nn] = f2bf(acc[mi][ni][r]);
      }
    }
  }
}

// Output projection: fp32 store + fp32 bias
__global__ __launch_bounds__(512, 2) void gemm_proj(
    const short* __restrict__ Aptr, const short* __restrict__ Bptr,
    float* __restrict__ C, const float* __restrict__ bias,
    int M, int K, int ldC) {
  __shared__ __attribute__((aligned(16))) short lds[3][24576];
  GEMM_MAIN_LOOP()

#pragma unroll
  for (int mi = 0; mi < 4; ++mi) {
    int mbase = m0 + wr * 64 + mi * 16 + quad * 4;
#pragma unroll
    for (int ni = 0; ni < 4; ++ni) {
      int n = n0 + wc * 64 + ni * 16 + lrow;
      float badd = bias[n];
#pragma unroll
      for (int r = 0; r < 4; ++r)
        C[(size_t)(mbase + r) * ldC + n] = acc[mi][ni][r] + badd;
    }
  }
}

// Flash attention, fixed-max softmax (M=12), row-sum via ones-row MFMA.
// Block = Q-tile pair {p, 31-p} for one (b,h); 33 K-tile iters each.
__global__ __launch_bounds__(256) void attn_kernel(
    const short* __restrict__ Q, const short* __restrict__ Kg,
    const short* __restrict__ Vt, const int* __restrict__ pm,
    short* __restrict__ ctx) {
  const int T = 2048, Cd = 2048, D = 128, MT = 4096;
  __shared__ __attribute__((aligned(16))) short Ks[64][136];
  __shared__ __attribute__((aligned(16))) short Vs[144][72];  // 128..143: ones/zero rows
  __shared__ __attribute__((aligned(16))) short Ps[4][16][72];

  const int tid  = threadIdx.x;
  const int lane = tid & 63;
  const int w    = tid >> 6;
  const int lrow = lane & 15;
  const int quad = lane >> 4;
  const int p = blockIdx.x, h = blockIdx.y, b = blockIdx.z;

  // init sum-helper rows: row 128 = 1.0 (bf16 0x3F80), rows 129..143 = 0
  for (int i = tid; i < 16 * 72; i += 256) {
    int rr = i / 72, cc = i % 72;
    Vs[128 + rr][cc] = (rr == 0) ? (short)0x3F80 : (short)0;
  }

#pragma unroll 1
  for (int tt = 0; tt < 2; ++tt) {
    const int qt = tt ? (31 - p) : p;
    const int q0 = qt * 64;
    const int qrow = q0 + w * 16 + quad * 4;

    vshort8 qf[4];
#pragma unroll
    for (int ks = 0; ks < 4; ++ks)
      qf[ks] = *(const vshort8*)(Q + (size_t)(b * T + q0 + w * 16 + lrow) * Cd +
                                 h * D + ks * 32 + quad * 8);
    bool keep[4];
#pragma unroll
    for (int r = 0; r < 4; ++r) keep[r] = pm[b * T + qrow + r] != 0;

    vfloat4 oacc[8] = {};
    vfloat4 osum = {};  // row-sum accumulator (col 0 = d128 ones-row)

    __syncthreads();
#pragma unroll
    for (int i = 0; i < 4; ++i) {
      int c = tid + i * 256;
      int kr = c >> 4, kc = c & 15;
      *(vfloat4*)(&Ks[kr][kc * 8]) =
          *(const vfloat4*)(Kg + (size_t)(b * T + kr) * Cd + h * D + kc * 8);
      int vr = c >> 3, vc = c & 7;
      *(vfloat4*)(&Vs[vr][vc * 8]) =
          *(const vfloat4*)(Vt + (size_t)(h * D + vr) * MT + b * T + vc * 8);
    }
    __syncthreads();

#pragma unroll 1
    for (int j = 0; j <= qt; ++j) {
      const int jn = (j < qt) ? (j + 1) : qt;
      vfloat4 pk[4], pv[4];
#pragma unroll
      for (int i = 0; i < 4; ++i) {
        int c = tid + i * 256;
        int kr = c >> 4, kc = c & 15;
        pk[i] = *(const vfloat4*)(Kg + (size_t)(b * T + jn * 64 + kr) * Cd + h * D + kc * 8);
        int vr = c >> 3, vc = c & 7;
        pv[i] = *(const vfloat4*)(Vt + (size_t)(h * D + vr) * MT + b * T + jn * 64 + vc * 8);
      }

      // QK^T
      vfloat4 sacc[4] = {};
#pragma unroll
      for (int nt = 0; nt < 4; ++nt)
#pragma unroll
        for (int ks = 0; ks < 4; ++ks) {
          vshort8 kf = *(const vshort8*)(&Ks[nt * 16 + lrow][ks * 32 + quad * 8]);
          sacc[nt] = __builtin_amdgcn_mfma_f32_16x16x32_bf16(qf[ks], kf, sacc[nt], 0, 0, 0);
        }

      // fixed-max softmax: p = exp(s - 12); padded rows -> s=0 (uniform);
      // causal future -> p = 0 exactly. Write P in A-layout via LDS.
#pragma unroll
      for (int nt = 0; nt < 4; ++nt) {
        int s_idx = j * 64 + nt * 16 + lrow;
#pragma unroll
        for (int r = 0; r < 4; ++r) {
          float sv = keep[r] ? sacc[nt][r] : 0.0f;
          float pe = __expf(sv - 12.0f);
          pe = (s_idx <= qrow + r) ? pe : 0.0f;
          Ps[w][quad * 4 + r][nt * 16 + lrow] = f2bf(pe);
        }
      }

      vshort8 pf[2];
#pragma unroll
      for (int kp = 0; kp < 2; ++kp)
        pf[kp] = *(const vshort8*)(&Ps[w][lrow][kp * 32 + quad * 8]);
#pragma unroll
      for (int dt = 0; dt < 8; ++dt)
#pragma unroll
        for (int kp = 0; kp < 2; ++kp) {
          vshort8 vf = *(const vshort8*)(&Vs[dt * 16 + lrow][kp * 32 + quad * 8]);
          oacc[dt] = __builtin_amdgcn_mfma_f32_16x16x32_bf16(pf[kp], vf, oacc[dt], 0, 0, 0);
        }
      // row sums via ones-row tile (d = 128..143)
#pragma unroll
      for (int kp = 0; kp < 2; ++kp) {
        vshort8 vf = *(const vshort8*)(&Vs[128 + lrow][kp * 32 + quad * 8]);
        osum = __builtin_amdgcn_mfma_f32_16x16x32_bf16(pf[kp], vf, osum, 0, 0, 0);
      }

      __syncthreads();
#pragma unroll
      for (int i = 0; i < 4; ++i) {
        int c = tid + i * 256;
        int kr = c >> 4, kc = c & 15;
        *(vfloat4*)(&Ks[kr][kc * 8]) = pk[i];
        int vr = c >> 3, vc = c & 7;
        *(vfloat4*)(&Vs[vr][vc * 8]) = pv[i];
      }
      __syncthreads();
    }

    // l[r] lives at col 0 of osum = lane quad*16, reg r
    float l[4];
#pragma unroll
    for (int r = 0; r < 4; ++r)
      l[r] = fmaxf(__shfl(osum[r], (lane & 48), 64), 1e-30f);

#pragma unroll
    for (int dt = 0; dt < 8; ++dt) {
      int d = dt * 16 + lrow;
#pragma unroll
      for (int r = 0; r < 4; ++r) {
        float o = oacc[dt][r] / l[r];
        ctx[(size_t)(b * T + qrow + r) * Cd + h * D + d] = f2bf(o);
      }
    }
  }
}

extern "C" void kernel_launch(void* const* d_in, const int* in_sizes, int n_in,
                              void* d_out, int out_size, void* d_ws, size_t ws_size,
                              hipStream_t stream) {
  (void)in_sizes; (void)n_in; (void)out_size; (void)ws_size;
  const float* x  = (const float*)d_in[0];
  const int*   pm = (const int*)d_in[1];
  const float* Wq = (const float*)d_in[2];
  const float* Wk = (const float*)d_in[3];
  const float* Wv = (const float*)d_in[4];
  const float* Wp = (const float*)d_in[5];
  const float* bp = (const float*)d_in[6];
  float* out = (float*)d_out;

  const int Bb = 2, T = 2048, Cd = 2048, M = Bb * T;  // M = 4096
  const size_t SZ = (size_t)M * Cd;   // 8.4M
  const size_t WZ = (size_t)Cd * Cd;  // 4.2M
  short* xb   = (short*)d_ws;         // [M][C]
  short* Qw   = xb + SZ;              // [M][C] (pre-scaled)
  short* Kw   = Qw + SZ;              // [M][C]
  short* Vtw  = Kw + SZ;              // [C][M]
  short* Cx   = Vtw + SZ;             // [M][C]
  short* wcat = Cx + SZ;              // [3C][C] QKV weights; reused for Wp

  const int CB = 256;
  dim3 gx(((int)SZ / 8 + CB - 1) / CB);
  dim3 gw(((int)WZ / 8 + CB - 1) / CB);
  const float scale = 0.08838834764831845f;  // 1/sqrt(128)

  cvt_kernel<<<gx, CB, 0, stream>>>(x, xb, (int)SZ);
  cvt3_kernel<<<dim3(gw.x, 3), CB, 0, stream>>>(Wq, Wk, Wv, wcat, (int)WZ);

  gemm_qkv<<<dim3(6144 / 256, M / 128), 512, 0, stream>>>(
      xb, wcat, Qw, Kw, Vtw, M, Cd, scale);

  attn_kernel<<<dim3(16, 16, Bb), 256, 0, stream>>>(Qw, Kw, Vtw, pm, Cx);

  cvt_kernel<<<gw, CB, 0, stream>>>(Wp, wcat, (int)WZ);
  gemm_proj<<<dim3(Cd / 256, M / 128), 512, 0, stream>>>(Cx, wcat, out, bp, M, Cd, Cd);
}